// Round 1
// baseline (239.238 us; speedup 1.0000x reference)
//
#include <hip/hip_runtime.h>

#define ETA_PLUS 1.2f
#define ETA_MINUS 0.5f
#define STEP_MIN 1e-6f
#define STEP_MAX 50.0f

__device__ __forceinline__ void irprop_elem(
    float p, float g, float s, float pg, float pu, bool loss_inc,
    float& new_p, float& new_s, float& new_pg, float& new_u)
{
    float sign = g * pg;
    float ns;
    if (sign > 0.0f)       ns = fminf(s * ETA_PLUS, STEP_MAX);
    else if (sign < 0.0f)  ns = fmaxf(s * ETA_MINUS, STEP_MIN);
    else                   ns = s;

    bool neg = (sign < 0.0f);
    float geff = (g > 0.0f) ? 1.0f : ((g < 0.0f) ? -1.0f : 0.0f);
    float upd = -ns * geff;
    if (neg) upd = loss_inc ? -pu : 0.0f;

    new_p  = p + upd;
    new_s  = ns;
    new_pg = neg ? 0.0f : g;
    new_u  = upd;
}

__global__ __launch_bounds__(256) void irprop_kernel(
    const float4* __restrict__ param,
    const float4* __restrict__ grad,
    const float4* __restrict__ stepsz,
    const float4* __restrict__ pgrad,
    const float4* __restrict__ pupd,
    const float* __restrict__ loss,
    const float* __restrict__ ploss,
    float4* __restrict__ out,   // [new_param | step_new | new_prev_grad | update], each n4 float4s
    int n4)
{
    const bool loss_inc = (loss[0] > ploss[0]);  // uniform, L2-broadcast
    const int stride = gridDim.x * blockDim.x;

    float4* out_p  = out;
    float4* out_s  = out + (size_t)n4;
    float4* out_pg = out + 2 * (size_t)n4;
    float4* out_u  = out + 3 * (size_t)n4;

    for (int i = blockIdx.x * blockDim.x + threadIdx.x; i < n4; i += stride) {
        float4 p  = param[i];
        float4 g  = grad[i];
        float4 s  = stepsz[i];
        float4 pg = pgrad[i];
        float4 pu = pupd[i];

        float4 rp, rs, rpg, ru;
        irprop_elem(p.x, g.x, s.x, pg.x, pu.x, loss_inc, rp.x, rs.x, rpg.x, ru.x);
        irprop_elem(p.y, g.y, s.y, pg.y, pu.y, loss_inc, rp.y, rs.y, rpg.y, ru.y);
        irprop_elem(p.z, g.z, s.z, pg.z, pu.z, loss_inc, rp.z, rs.z, rpg.z, ru.z);
        irprop_elem(p.w, g.w, s.w, pg.w, pu.w, loss_inc, rp.w, rs.w, rpg.w, ru.w);

        out_p[i]  = rp;
        out_s[i]  = rs;
        out_pg[i] = rpg;
        out_u[i]  = ru;
    }
}

extern "C" void kernel_launch(void* const* d_in, const int* in_sizes, int n_in,
                              void* d_out, int out_size, void* d_ws, size_t ws_size,
                              hipStream_t stream) {
    const float* param  = (const float*)d_in[0];
    const float* grad   = (const float*)d_in[1];
    const float* stepsz = (const float*)d_in[2];
    const float* pgrad  = (const float*)d_in[3];
    const float* pupd   = (const float*)d_in[4];
    const float* loss   = (const float*)d_in[5];
    const float* ploss  = (const float*)d_in[6];

    int n  = in_sizes[0];
    int n4 = n / 4;  // N = 2^25, divisible by 4

    const int block = 256;
    int grid = (n4 + block - 1) / block;
    if (grid > 2048) grid = 2048;  // grid-stride the rest (memory-bound, G11)

    irprop_kernel<<<grid, block, 0, stream>>>(
        (const float4*)param, (const float4*)grad, (const float4*)stepsz,
        (const float4*)pgrad, (const float4*)pupd,
        loss, ploss, (float4*)d_out, n4);
}

// Round 3
// 226.011 us; speedup vs baseline: 1.0585x; 1.0585x over previous
//
#include <hip/hip_runtime.h>

#define ETA_PLUS 1.2f
#define ETA_MINUS 0.5f
#define STEP_MIN 1e-6f
#define STEP_MAX 50.0f

typedef float vfloat4 __attribute__((ext_vector_type(4)));  // clang vector: OK for nontemporal builtins

__device__ __forceinline__ void irprop_elem(
    float p, float g, float s, float pg, float pu, bool loss_inc,
    float& new_p, float& new_s, float& new_pg, float& new_u)
{
    float sign = g * pg;
    float ns;
    if (sign > 0.0f)       ns = fminf(s * ETA_PLUS, STEP_MAX);
    else if (sign < 0.0f)  ns = fmaxf(s * ETA_MINUS, STEP_MIN);
    else                   ns = s;

    bool neg = (sign < 0.0f);
    float geff = (g > 0.0f) ? 1.0f : ((g < 0.0f) ? -1.0f : 0.0f);
    float upd = -ns * geff;
    if (neg) upd = loss_inc ? -pu : 0.0f;

    new_p  = p + upd;
    new_s  = ns;
    new_pg = neg ? 0.0f : g;
    new_u  = upd;
}

__global__ __launch_bounds__(256) void irprop_kernel(
    const vfloat4* __restrict__ param,
    const vfloat4* __restrict__ grad,
    const vfloat4* __restrict__ stepsz,
    const vfloat4* __restrict__ pgrad,
    const vfloat4* __restrict__ pupd,
    const float* __restrict__ loss,
    const float* __restrict__ ploss,
    vfloat4* __restrict__ out,   // [new_param | step_new | new_prev_grad | update]
    int n4)
{
    const int i = blockIdx.x * blockDim.x + threadIdx.x;
    if (i >= n4) return;

    const bool loss_inc = (loss[0] > ploss[0]);  // uniform, cached broadcast

    // single-touch streaming data: non-temporal to skip cache pollution
    vfloat4 p  = __builtin_nontemporal_load(&param[i]);
    vfloat4 g  = __builtin_nontemporal_load(&grad[i]);
    vfloat4 s  = __builtin_nontemporal_load(&stepsz[i]);
    vfloat4 pg = __builtin_nontemporal_load(&pgrad[i]);
    vfloat4 pu = __builtin_nontemporal_load(&pupd[i]);

    vfloat4 rp, rs, rpg, ru;
    #pragma unroll
    for (int j = 0; j < 4; ++j) {
        float a, b, c, d;
        irprop_elem(p[j], g[j], s[j], pg[j], pu[j], loss_inc, a, b, c, d);
        rp[j] = a; rs[j] = b; rpg[j] = c; ru[j] = d;
    }

    __builtin_nontemporal_store(rp,  &out[i]);
    __builtin_nontemporal_store(rs,  &out[(size_t)n4 + i]);
    __builtin_nontemporal_store(rpg, &out[2 * (size_t)n4 + i]);
    __builtin_nontemporal_store(ru,  &out[3 * (size_t)n4 + i]);
}

extern "C" void kernel_launch(void* const* d_in, const int* in_sizes, int n_in,
                              void* d_out, int out_size, void* d_ws, size_t ws_size,
                              hipStream_t stream) {
    const float* param  = (const float*)d_in[0];
    const float* grad   = (const float*)d_in[1];
    const float* stepsz = (const float*)d_in[2];
    const float* pgrad  = (const float*)d_in[3];
    const float* pupd   = (const float*)d_in[4];
    const float* loss   = (const float*)d_in[5];
    const float* ploss  = (const float*)d_in[6];

    int n  = in_sizes[0];
    int n4 = n / 4;  // N = 2^25, divisible by 4

    const int block = 256;
    int grid = (n4 + block - 1) / block;  // exact grid: 1 float4-bundle per thread

    irprop_kernel<<<grid, block, 0, stream>>>(
        (const vfloat4*)param, (const vfloat4*)grad, (const vfloat4*)stepsz,
        (const vfloat4*)pgrad, (const vfloat4*)pupd,
        loss, ploss, (vfloat4*)d_out, n4);
}